// Round 8
// baseline (362.371 us; speedup 1.0000x reference)
//
#include <hip/hip_runtime.h>
#include <hip/hip_bf16.h>

#define N_SITES 100000
#define C_IN 256
#define C_MID 64
#define C_OUT 256

typedef __attribute__((ext_vector_type(8))) short bf16x8;   // 8 bf16 in 4 VGPRs
typedef __attribute__((ext_vector_type(4))) float f32x4;    // MFMA C/D frag

__device__ inline short f2bf(float f) {
  return __builtin_bit_cast(short, __float2bfloat16(f));
}

__device__ inline f32x4 mfma16(bf16x8 a, bf16x8 b, f32x4 c) {
  return __builtin_amdgcn_mfma_f32_16x16x32_bf16(a, b, c, 0, 0, 0);
}

// ---------------------------------------------------------------------------
// Prep: W1T[n][k] = W1[k][n] (bf16), W2T[k][dout][din] = W2[k][din][dout],
//       W3T[n][k] = W3[k][n], zero h1 pad row (row N_SITES).
// ---------------------------------------------------------------------------
__global__ __launch_bounds__(256) void k_prep(const float* __restrict__ W1,
                                              const float* __restrict__ W2,
                                              const float* __restrict__ W3,
                                              short* __restrict__ W1T,
                                              short* __restrict__ W2T,
                                              short* __restrict__ W3T,
                                              short* __restrict__ h1) {
  int i = blockIdx.x * 256 + threadIdx.x;
  if (i < 16384) {                       // W1T: [64][256]
    int n = i >> 8, k = i & 255;
    W1T[i] = f2bf(W1[k * 64 + n]);
  } else if (i < 16384 + 110592) {       // W2T: [27][64][64]
    int j = i - 16384;
    int k = j >> 12, rem = j & 4095;
    int dout = rem >> 6, din = rem & 63;
    W2T[j] = f2bf(W2[k * 4096 + din * 64 + dout]);
  } else if (i < 16384 + 110592 + 16384) {  // W3T: [256][64]
    int j = i - (16384 + 110592);
    int n = j >> 6, k = j & 63;
    W3T[j] = f2bf(W3[k * 256 + n]);
  } else if (i < 16384 + 110592 + 16384 + 64) {  // h1 pad row
    h1[(size_t)N_SITES * 64 + (i - (16384 + 110592 + 16384))] = 0;
  }
}

// ---------------------------------------------------------------------------
// conv1: h1[n][c] = relu(g1[c] * (F @ W1)[n][c] + b1[c]), bf16 out.
// 32 rows/wave (halves W1T reload traffic vs 16), 4 waves/block = 128 rows.
// ---------------------------------------------------------------------------
__global__ __launch_bounds__(256) void k_conv1(const float* __restrict__ F,
                                               const short* __restrict__ W1T,
                                               const float* __restrict__ g1,
                                               const float* __restrict__ b1,
                                               short* __restrict__ h1) {
  int tid = threadIdx.x;
  int lane = tid & 63, wave = tid >> 6;
  int l15 = lane & 15, l4 = lane >> 4;
  int base = blockIdx.x * 128 + wave * 32;

  int r0 = base + l15;       r0 = r0 < N_SITES ? r0 : (N_SITES - 1);
  int r1 = base + 16 + l15;  r1 = r1 < N_SITES ? r1 : (N_SITES - 1);
  const float* f0 = F + (size_t)r0 * 256 + l4 * 8;
  const float* f1 = F + (size_t)r1 * 256 + l4 * 8;

  f32x4 acc[2][4];
#pragma unroll
  for (int mf = 0; mf < 2; ++mf)
#pragma unroll
    for (int nf = 0; nf < 4; ++nf) acc[mf][nf] = (f32x4){0.f, 0.f, 0.f, 0.f};

#pragma unroll
  for (int kk = 0; kk < 8; ++kk) {
    float4 x00 = *(const float4*)(f0 + kk * 32);
    float4 x01 = *(const float4*)(f0 + kk * 32 + 4);
    float4 x10 = *(const float4*)(f1 + kk * 32);
    float4 x11 = *(const float4*)(f1 + kk * 32 + 4);
    bf16x8 a0, a1;
    a0[0] = f2bf(x00.x); a0[1] = f2bf(x00.y); a0[2] = f2bf(x00.z); a0[3] = f2bf(x00.w);
    a0[4] = f2bf(x01.x); a0[5] = f2bf(x01.y); a0[6] = f2bf(x01.z); a0[7] = f2bf(x01.w);
    a1[0] = f2bf(x10.x); a1[1] = f2bf(x10.y); a1[2] = f2bf(x10.z); a1[3] = f2bf(x10.w);
    a1[4] = f2bf(x11.x); a1[5] = f2bf(x11.y); a1[6] = f2bf(x11.z); a1[7] = f2bf(x11.w);
#pragma unroll
    for (int nf = 0; nf < 4; ++nf) {
      bf16x8 bf = *(const bf16x8*)(W1T + (nf * 16 + l15) * 256 + kk * 32 + l4 * 8);
      acc[0][nf] = mfma16(a0, bf, acc[0][nf]);
      acc[1][nf] = mfma16(a1, bf, acc[1][nf]);
    }
  }

#pragma unroll
  for (int mf = 0; mf < 2; ++mf) {
#pragma unroll
    for (int nf = 0; nf < 4; ++nf) {
      int col = nf * 16 + l15;
      float g = g1[col], bb = b1[col];
#pragma unroll
      for (int r = 0; r < 4; ++r) {
        int site = base + mf * 16 + l4 * 4 + r;
        if (site < N_SITES) {
          float v = fmaxf(acc[mf][nf][r] * g + bb, 0.f);
          h1[(size_t)site * 64 + col] = f2bf(v);
        }
      }
    }
  }
}

// ---------------------------------------------------------------------------
// conv2: gather-GEMM over 27 neighbors. K-SPLIT across wave pairs:
// 4 waves/block, 128 rows. wave = (whi, wlo): wlo = row-half (64 rows),
// whi = k-half (0..12 / 13..26). Doubles resident waves/CU vs r7 at the
// same B-reload traffic. LDS fp32 reduce combines the two k-halves.
// ---------------------------------------------------------------------------
__global__ __launch_bounds__(256) void k_conv2(const short* __restrict__ h1,
                                               const short* __restrict__ W2T,
                                               const float* __restrict__ g2,
                                               const float* __restrict__ b2,
                                               const int* __restrict__ NB,
                                               short* __restrict__ h2) {
  __shared__ int nbt[128 * 27];
  __shared__ float red[128][68];   // +4 pad: 2-way worst-case bank aliasing
  int tid = threadIdx.x;

  // XCD-chunked bijective swizzle (m204 formula)
  int nwg = gridDim.x;
  int q = nwg >> 3, r = nwg & 7;
  int xcd = blockIdx.x & 7, idx = blockIdx.x >> 3;
  int swz = (xcd < r) ? (xcd * (q + 1) + idx)
                      : (r * (q + 1) + (xcd - r) * q + idx);
  int blockbase = swz * 128;

  for (int i = tid; i < 128 * 27; i += 256) {
    int site = blockbase + i / 27;
    nbt[i] = (site < N_SITES) ? NB[(size_t)site * 27 + (i % 27)] : N_SITES;
  }
  __syncthreads();

  int lane = tid & 63, wave = tid >> 6;
  int l15 = lane & 15, l4 = lane >> 4;
  int wlo = wave & 1, whi = wave >> 1;
  int wrow = wlo * 64 + l15;
  int kbeg = whi ? 13 : 0;
  int kend = whi ? 27 : 13;

  f32x4 acc[4][4];              // [mf][nf]
#pragma unroll
  for (int mf = 0; mf < 4; ++mf)
#pragma unroll
    for (int nf = 0; nf < 4; ++nf) acc[mf][nf] = (f32x4){0.f, 0.f, 0.f, 0.f};

  bf16x8 bufA[4][2], bufB[4][2];

#define LOADBUF(BUF, KK)                                                    \
  {                                                                         \
    _Pragma("unroll")                                                       \
    for (int mf = 0; mf < 4; ++mf) {                                        \
      int n = nbt[(wrow + mf * 16) * 27 + (KK)];                            \
      const short* p = h1 + (size_t)n * 64 + l4 * 8;                        \
      BUF[mf][0] = *(const bf16x8*)p;                                       \
      BUF[mf][1] = *(const bf16x8*)(p + 32);                                \
    }                                                                       \
  }

#define COMPUTE(BUF, KK)                                                    \
  {                                                                         \
    const short* wk = W2T + (size_t)(KK) * 4096 + l15 * 64 + l4 * 8;        \
    _Pragma("unroll")                                                       \
    for (int nf = 0; nf < 4; ++nf) {                                        \
      bf16x8 b0 = *(const bf16x8*)(wk + nf * 1024);                         \
      bf16x8 b1 = *(const bf16x8*)(wk + nf * 1024 + 32);                    \
      _Pragma("unroll")                                                     \
      for (int mf = 0; mf < 4; ++mf) {                                      \
        acc[mf][nf] = mfma16(BUF[mf][0], b0, acc[mf][nf]);                  \
        acc[mf][nf] = mfma16(BUF[mf][1], b1, acc[mf][nf]);                  \
      }                                                                     \
    }                                                                       \
  }

  int k = kbeg;
  LOADBUF(bufA, kbeg);
  while (k + 2 <= kend) {
    LOADBUF(bufB, k + 1);
    COMPUTE(bufA, k);
    LOADBUF(bufA, (k + 2 < kend) ? k + 2 : k + 1);  // clamped (dead on last)
    COMPUTE(bufB, k + 1);
    k += 2;
  }
  if (k < kend) COMPUTE(bufA, k);   // odd trip-count tail

#undef LOADBUF
#undef COMPUTE

  // k-half reduce: whi=1 waves publish partials, whi=0 waves combine + write.
  if (whi) {
#pragma unroll
    for (int mf = 0; mf < 4; ++mf)
#pragma unroll
      for (int nf = 0; nf < 4; ++nf)
#pragma unroll
        for (int rr = 0; rr < 4; ++rr)
          red[wlo * 64 + mf * 16 + l4 * 4 + rr][nf * 16 + l15] = acc[mf][nf][rr];
  }
  __syncthreads();
  if (!whi) {
#pragma unroll
    for (int mf = 0; mf < 4; ++mf) {
#pragma unroll
      for (int nf = 0; nf < 4; ++nf) {
        int col = nf * 16 + l15;
        float g = g2[col], bb = b2[col];
#pragma unroll
        for (int rr = 0; rr < 4; ++rr) {
          int row = wlo * 64 + mf * 16 + l4 * 4 + rr;
          int site = blockbase + row;
          if (site < N_SITES) {
            float v = acc[mf][nf][rr] + red[row][col];
            h2[(size_t)site * 64 + col] = f2bf(fmaxf(v * g + bb, 0.f));
          }
        }
      }
    }
  }
}

// ---------------------------------------------------------------------------
// conv3 + affine + residual + relu, fp32 out. Chan-split: each wave owns
// 64 out-chans x 64 sites (acc[4][4]); per-block W3T read ONCE (traffic /4).
// Swapped operands: A = W3T rows=chans, B = h2 rows=sites -> D[chan][site];
// lane holds 4 consecutive chans of one site -> float4 residual+store.
// ---------------------------------------------------------------------------
__global__ __launch_bounds__(256) void k_conv3(const short* __restrict__ h2,
                                               const short* __restrict__ W3T,
                                               const float* __restrict__ g3,
                                               const float* __restrict__ b3,
                                               const float* __restrict__ F,
                                               float* __restrict__ out) {
  int tid = threadIdx.x;
  int lane = tid & 63, wave = tid >> 6;
  int l15 = lane & 15, l4 = lane >> 4;
  int sbase = blockIdx.x * 64;

  bf16x8 bv[4][2];
#pragma unroll
  for (int sf = 0; sf < 4; ++sf) {
    int s = sbase + sf * 16 + l15;
    s = s < N_SITES ? s : (N_SITES - 1);
    const short* pb = h2 + (size_t)s * 64 + l4 * 8;
    bv[sf][0] = *(const bf16x8*)pb;
    bv[sf][1] = *(const bf16x8*)(pb + 32);
  }

  f32x4 acc[4][4];   // [cf][sf]
#pragma unroll
  for (int cf = 0; cf < 4; ++cf)
#pragma unroll
    for (int sf = 0; sf < 4; ++sf) acc[cf][sf] = (f32x4){0.f, 0.f, 0.f, 0.f};

#pragma unroll
  for (int cf = 0; cf < 4; ++cf) {
    const short* pa = W3T + (size_t)(wave * 64 + cf * 16 + l15) * 64 + l4 * 8;
    bf16x8 a0 = *(const bf16x8*)pa;
    bf16x8 a1 = *(const bf16x8*)(pa + 32);
#pragma unroll
    for (int sf = 0; sf < 4; ++sf) {
      acc[cf][sf] = mfma16(a0, bv[sf][0], acc[cf][sf]);
      acc[cf][sf] = mfma16(a1, bv[sf][1], acc[cf][sf]);
    }
  }

#pragma unroll
  for (int cf = 0; cf < 4; ++cf) {
    int chan = wave * 64 + cf * 16 + l4 * 4;   // D row = chan
    float4 g = *(const float4*)(g3 + chan);
    float4 bb = *(const float4*)(b3 + chan);
#pragma unroll
    for (int sf = 0; sf < 4; ++sf) {
      int site = sbase + sf * 16 + l15;        // D col = site
      if (site < N_SITES) {
        size_t o = (size_t)site * 256 + chan;
        float4 fv = *(const float4*)(F + o);
        float4 rr;
        rr.x = fmaxf(acc[cf][sf][0] * g.x + bb.x + fv.x, 0.f);
        rr.y = fmaxf(acc[cf][sf][1] * g.y + bb.y + fv.y, 0.f);
        rr.z = fmaxf(acc[cf][sf][2] * g.z + bb.z + fv.z, 0.f);
        rr.w = fmaxf(acc[cf][sf][3] * g.w + bb.w + fv.w, 0.f);
        *(float4*)(out + o) = rr;
      }
    }
  }
}

// ---------------------------------------------------------------------------
extern "C" void kernel_launch(void* const* d_in, const int* in_sizes, int n_in,
                              void* d_out, int out_size, void* d_ws, size_t ws_size,
                              hipStream_t stream) {
  const float* F  = (const float*)d_in[0];
  const float* W1 = (const float*)d_in[1];
  const float* W2 = (const float*)d_in[2];
  const float* W3 = (const float*)d_in[3];
  const float* g1 = (const float*)d_in[4];
  const float* b1 = (const float*)d_in[5];
  const float* g2 = (const float*)d_in[6];
  const float* b2 = (const float*)d_in[7];
  const float* g3 = (const float*)d_in[8];
  const float* b3 = (const float*)d_in[9];
  const int*   NB = (const int*)d_in[10];
  float* out = (float*)d_out;

  char* ws = (char*)d_ws;
  short* W1T = (short*)(ws);                                   // 32768 B
  short* W2T = (short*)(ws + 32768);                           // 221184 B
  short* W3T = (short*)(ws + 32768 + 221184);                  // 32768 B
  short* h1  = (short*)(ws + 32768 + 221184 + 32768);          // (N+1)*64*2 = 12800128 B
  short* h2  = (short*)(ws + 32768 + 221184 + 32768 + 12800128); // N*64*2 B

  k_prep<<<dim3(561), dim3(256), 0, stream>>>(W1, W2, W3, W1T, W2T, W3T, h1);
  k_conv1<<<dim3((N_SITES + 127) / 128), dim3(256), 0, stream>>>(F, W1T, g1, b1, h1);
  k_conv2<<<dim3((N_SITES + 127) / 128), dim3(256), 0, stream>>>(h1, W2T, g2, b2, NB, h2);
  k_conv3<<<dim3((N_SITES + 63) / 64), dim3(256), 0, stream>>>(h2, W3T, g3, b3, F, out);
}